// Round 5
// baseline (1202.283 us; speedup 1.0000x reference)
//
#include <hip/hip_runtime.h>
#include <math.h>

#define DIM 512
#define NCLS 100
#define NS 2048
#define DD (DIM*DIM)
#define SHRINKV 1e-4f

typedef short bf16x8 __attribute__((ext_vector_type(8)));
typedef short s16x4 __attribute__((ext_vector_type(4)));
typedef float f32x4 __attribute__((ext_vector_type(4)));

static __device__ __forceinline__ short f2bf(float f) {
  unsigned int u = __float_as_uint(f);
  u += 0x7FFFu + ((u >> 16) & 1u);   // round-to-nearest-even
  return (short)(u >> 16);
}

// Build M_k = (1-sh)*(0.5*(SigmaK_k+Sigma)) + sh*I ; accumulate ||RegSigma||_F^2
// into aux[1+k] via atomics (aux zeroed by hipMemsetAsync before launch).
__global__ __launch_bounds__(256) void prep_kernel(const float* __restrict__ SigmaK,
                                                   const float* __restrict__ Sigma,
                                                   float* __restrict__ M,
                                                   float* __restrict__ aux) {
  int b = blockIdx.x;
  int k = b >> 2, chunk = b & 3;
  const float* Sk = SigmaK + (size_t)k * DD;
  float* Mk = M + (size_t)k * DD;
  int base0 = chunk << 16;
  float fro = 0.f;
  const float oms = 1.0f - SHRINKV;
  for (int it = 0; it < 64; ++it) {
    int idx = base0 + (it << 10) + (threadIdx.x << 2);
    float4 a = *(const float4*)(Sk + idx);
    float4 g = *(const float4*)(Sigma + idx);
    int r = idx >> 9, c = idx & 511;
    float4 reg;
    reg.x = 0.5f*(a.x + g.x); reg.y = 0.5f*(a.y + g.y);
    reg.z = 0.5f*(a.z + g.z); reg.w = 0.5f*(a.w + g.w);
    fro += reg.x*reg.x + reg.y*reg.y + reg.z*reg.z + reg.w*reg.w;
    float4 m;
    m.x = oms*reg.x + ((r == c + 0) ? SHRINKV : 0.f);
    m.y = oms*reg.y + ((r == c + 1) ? SHRINKV : 0.f);
    m.z = oms*reg.z + ((r == c + 2) ? SHRINKV : 0.f);
    m.w = oms*reg.w + ((r == c + 3) ? SHRINKV : 0.f);
    *(float4*)(Mk + idx) = m;
  }
  __shared__ float red[4];
  int lane = threadIdx.x & 63, w = threadIdx.x >> 6;
  for (int o = 32; o > 0; o >>= 1) fro += __shfl_down(fro, o);
  if (lane == 0) red[w] = fro;
  __syncthreads();
  if (threadIdx.x == 0) atomicAdd(&aux[1 + k], red[0] + red[1] + red[2] + red[3]);
}

// Fused fdiag + trsm for panel p. One 256-thread WG per class.
// Wave 0: shuffle-Cholesky of block (p,p), triangular inverse into M(p,p) f32,
// W(p,p) bf16, and invT[m][c] = inv[c][m] in LDS (TRANSPOSED — the GEMM's B
// operand, so TRSM computes A_ip * inv^T). Then all waves: 64^3 GEMMs.
__global__ __launch_bounds__(256) void fdt_kernel(float* __restrict__ M,
                                                  short* __restrict__ Wb, int p) {
  __shared__ float Llds[64 * 68];
  __shared__ float invT[64 * 68];
  __shared__ float TA[64 * 68];
  int kcls = blockIdx.x;
  float* Mk = M + (size_t)kcls * DD;
  short* Wk = Wb + (size_t)kcls * DD;
  int tid = threadIdx.x, lane = tid & 63, wv = tid >> 6;
  int ty = tid >> 4, tx = tid & 15;
  int sr = tid >> 2, sq = (tid & 3) << 4;
  int p0 = p << 6;
  if (wv == 0) {
    float row[64];
    const float* src = Mk + (size_t)(p0 + lane) * DIM + p0;
    #pragma unroll
    for (int c4 = 0; c4 < 64; c4 += 4) {
      float4 v = *(const float4*)(src + c4);
      row[c4] = v.x; row[c4+1] = v.y; row[c4+2] = v.z; row[c4+3] = v.w;
    }
    #pragma unroll
    for (int j = 0; j < 64; ++j) {
      float diagv = __shfl(row[j], j);
      float dv = sqrtf(diagv);
      float rinv = 1.0f / dv;
      float myLj = row[j] * rinv;
      row[j] = myLj;
      #pragma unroll
      for (int c = j + 1; c < 64; ++c)
        row[c] = fmaf(-myLj, __shfl(myLj, c), row[c]);
    }
    #pragma unroll
    for (int c = 0; c < 64; ++c)
      Llds[lane * 68 + c] = (c <= lane) ? row[c] : 0.f;
  }
  __syncthreads();
  if (wv == 0) {
    float w[64];   // lane holds column `lane` of inv: w[r] = inv[r][lane]
    #pragma unroll
    for (int r = 0; r < 64; ++r) {
      float s = 0.f;
      #pragma unroll
      for (int kk = 0; kk + 4 <= r; kk += 4) {
        float4 lv = *(const float4*)(Llds + r*68 + kk);
        s += lv.x*w[kk] + lv.y*w[kk+1] + lv.z*w[kk+2] + lv.w*w[kk+3];
      }
      #pragma unroll
      for (int kk = r & ~3; kk < r; ++kk) s += Llds[r*68 + kk] * w[kk];
      float rhs = ((r == lane) ? 1.0f : 0.0f) - s;
      w[r] = rhs / Llds[r*68 + r];   // exact 0 for r < lane
    }
    #pragma unroll
    for (int r = 0; r < 64; ++r) {
      Mk[(size_t)(p0 + r)*DIM + p0 + lane] = w[r];
      Wk[(size_t)(p0 + r)*DIM + p0 + lane] = f2bf(w[r]);
      invT[lane*68 + r] = w[r];   // invT[m][c] = inv[c][m]  (m=lane, c=r)
    }
  }
  __syncthreads();
  for (int i = p + 1; i < 8; ++i) {
    {
      const float* a = Mk + (size_t)((i << 6) + sr)*DIM + p0 + sq;
      #pragma unroll
      for (int t4 = 0; t4 < 4; ++t4) {
        float4 va = *(const float4*)(a + 4*t4);
        TA[(sq+4*t4+0)*68+sr]=va.x; TA[(sq+4*t4+1)*68+sr]=va.y;
        TA[(sq+4*t4+2)*68+sr]=va.z; TA[(sq+4*t4+3)*68+sr]=va.w;
      }
    }
    __syncthreads();
    float acc[4][4];
    #pragma unroll
    for (int a2 = 0; a2 < 4; ++a2)
      #pragma unroll
      for (int b2 = 0; b2 < 4; ++b2) acc[a2][b2] = 0.f;
    #pragma unroll 16
    for (int m = 0; m < 64; ++m) {
      float4 av = *(const float4*)(TA + m*68 + (ty << 2));
      float4 bv = *(const float4*)(invT + m*68 + (tx << 2));
      float a4[4] = {av.x, av.y, av.z, av.w};
      float b4[4] = {bv.x, bv.y, bv.z, bv.w};
      #pragma unroll
      for (int ir = 0; ir < 4; ++ir)
        #pragma unroll
        for (int ic = 0; ic < 4; ++ic) acc[ir][ic] += a4[ir] * b4[ic];
    }
    #pragma unroll
    for (int q = 0; q < 4; ++q) {
      float4 v; v.x = acc[q][0]; v.y = acc[q][1]; v.z = acc[q][2]; v.w = acc[q][3];
      *(float4*)(Mk + (size_t)((i << 6) + (ty << 2) + q)*DIM + p0 + (tx << 2)) = v;
    }
    __syncthreads();   // TA reusable next iteration
  }
}

// SYRK: for p < j <= i, A_ij -= L_ip * L_jp^T. One WG per (class, pair).
__global__ __launch_bounds__(256) void syrk_kernel(float* __restrict__ M, int p) {
  __shared__ float TA[64 * 68];
  __shared__ float TB[64 * 68];
  int n = 7 - p;
  int T = n * (n + 1) / 2;
  int cls = blockIdx.x / T;
  int t = blockIdx.x % T;
  int bi = 0;
  while (t > bi) { t -= bi + 1; ++bi; }
  int i = p + 1 + bi, j = p + 1 + t;
  float* Mk = M + (size_t)cls * DD;
  int tid = threadIdx.x;
  int ty = tid >> 4, tx = tid & 15;
  int sr = tid >> 2, sq = (tid & 3) << 4;
  {
    const float* a = Mk + (size_t)((i << 6) + sr)*DIM + (p << 6) + sq;
    const float* b = Mk + (size_t)((j << 6) + sr)*DIM + (p << 6) + sq;
    #pragma unroll
    for (int t4 = 0; t4 < 4; ++t4) {
      float4 va = *(const float4*)(a + 4*t4);
      TA[(sq+4*t4+0)*68+sr]=va.x; TA[(sq+4*t4+1)*68+sr]=va.y;
      TA[(sq+4*t4+2)*68+sr]=va.z; TA[(sq+4*t4+3)*68+sr]=va.w;
      float4 vb = *(const float4*)(b + 4*t4);
      TB[(sq+4*t4+0)*68+sr]=vb.x; TB[(sq+4*t4+1)*68+sr]=vb.y;
      TB[(sq+4*t4+2)*68+sr]=vb.z; TB[(sq+4*t4+3)*68+sr]=vb.w;
    }
  }
  __syncthreads();
  float acc[4][4];
  #pragma unroll
  for (int a = 0; a < 4; ++a)
    #pragma unroll
    for (int b = 0; b < 4; ++b) acc[a][b] = 0.f;
  #pragma unroll 16
  for (int m = 0; m < 64; ++m) {
    float4 av = *(const float4*)(TA + m*68 + (ty << 2));
    float4 bv = *(const float4*)(TB + m*68 + (tx << 2));
    float a4[4] = {av.x, av.y, av.z, av.w};
    float b4[4] = {bv.x, bv.y, bv.z, bv.w};
    #pragma unroll
    for (int ir = 0; ir < 4; ++ir)
      #pragma unroll
      for (int ic = 0; ic < 4; ++ic) acc[ir][ic] += a4[ir] * b4[ic];
  }
  #pragma unroll
  for (int q = 0; q < 4; ++q) {
    float* dst = Mk + (size_t)((i << 6) + (ty << 2) + q)*DIM + (j << 6) + (tx << 2);
    float4 v = *(const float4*)dst;
    v.x -= acc[q][0]; v.y -= acc[q][1]; v.z -= acc[q][2]; v.w -= acc[q][3];
    *(float4*)dst = v;
  }
}

// Tail: panels 4..7 fused per class (fdiag + trsm + syrk in-WG).
__global__ __launch_bounds__(256) void tail_kernel(float* __restrict__ M,
                                                   short* __restrict__ Wb) {
  __shared__ float Llds[64 * 68];
  __shared__ float invT[64 * 68];
  __shared__ float TA[64 * 68];
  __shared__ float TB[64 * 68];
  int kcls = blockIdx.x;
  float* Mk = M + (size_t)kcls * DD;
  short* Wk = Wb + (size_t)kcls * DD;
  int tid = threadIdx.x, lane = tid & 63, wv = tid >> 6;
  int ty = tid >> 4, tx = tid & 15;
  int sr = tid >> 2, sq = (tid & 3) << 4;
  for (int p = 4; p < 8; ++p) {
    int p0 = p << 6;
    __syncthreads();   // previous panel's syrk writes visible
    if (wv == 0) {
      float row[64];
      const float* src = Mk + (size_t)(p0 + lane) * DIM + p0;
      #pragma unroll
      for (int c4 = 0; c4 < 64; c4 += 4) {
        float4 v = *(const float4*)(src + c4);
        row[c4] = v.x; row[c4+1] = v.y; row[c4+2] = v.z; row[c4+3] = v.w;
      }
      #pragma unroll
      for (int j = 0; j < 64; ++j) {
        float diagv = __shfl(row[j], j);
        float dv = sqrtf(diagv);
        float rinv = 1.0f / dv;
        float myLj = row[j] * rinv;
        row[j] = myLj;
        #pragma unroll
        for (int c = j + 1; c < 64; ++c)
          row[c] = fmaf(-myLj, __shfl(myLj, c), row[c]);
      }
      #pragma unroll
      for (int c = 0; c < 64; ++c)
        Llds[lane * 68 + c] = (c <= lane) ? row[c] : 0.f;
    }
    __syncthreads();
    if (wv == 0) {
      float w[64];
      #pragma unroll
      for (int r = 0; r < 64; ++r) {
        float s = 0.f;
        #pragma unroll
        for (int kk = 0; kk + 4 <= r; kk += 4) {
          float4 lv = *(const float4*)(Llds + r*68 + kk);
          s += lv.x*w[kk] + lv.y*w[kk+1] + lv.z*w[kk+2] + lv.w*w[kk+3];
        }
        #pragma unroll
        for (int kk = r & ~3; kk < r; ++kk) s += Llds[r*68 + kk] * w[kk];
        float rhs = ((r == lane) ? 1.0f : 0.0f) - s;
        w[r] = rhs / Llds[r*68 + r];
      }
      #pragma unroll
      for (int r = 0; r < 64; ++r) {
        Mk[(size_t)(p0 + r)*DIM + p0 + lane] = w[r];
        Wk[(size_t)(p0 + r)*DIM + p0 + lane] = f2bf(w[r]);
        invT[lane*68 + r] = w[r];   // invT[m][c] = inv[c][m]  (m=lane, c=r)
      }
    }
    __syncthreads();
    // trsm
    for (int i = p + 1; i < 8; ++i) {
      {
        const float* a = Mk + (size_t)((i << 6) + sr)*DIM + p0 + sq;
        #pragma unroll
        for (int t4 = 0; t4 < 4; ++t4) {
          float4 va = *(const float4*)(a + 4*t4);
          TA[(sq+4*t4+0)*68+sr]=va.x; TA[(sq+4*t4+1)*68+sr]=va.y;
          TA[(sq+4*t4+2)*68+sr]=va.z; TA[(sq+4*t4+3)*68+sr]=va.w;
        }
      }
      __syncthreads();
      float acc[4][4];
      #pragma unroll
      for (int a2 = 0; a2 < 4; ++a2)
        #pragma unroll
        for (int b2 = 0; b2 < 4; ++b2) acc[a2][b2] = 0.f;
      #pragma unroll 16
      for (int m = 0; m < 64; ++m) {
        float4 av = *(const float4*)(TA + m*68 + (ty << 2));
        float4 bv = *(const float4*)(invT + m*68 + (tx << 2));
        float a4[4] = {av.x, av.y, av.z, av.w};
        float b4[4] = {bv.x, bv.y, bv.z, bv.w};
        #pragma unroll
        for (int ir = 0; ir < 4; ++ir)
          #pragma unroll
          for (int ic = 0; ic < 4; ++ic) acc[ir][ic] += a4[ir] * b4[ic];
      }
      #pragma unroll
      for (int q = 0; q < 4; ++q) {
        float4 v; v.x = acc[q][0]; v.y = acc[q][1]; v.z = acc[q][2]; v.w = acc[q][3];
        *(float4*)(Mk + (size_t)((i << 6) + (ty << 2) + q)*DIM + p0 + (tx << 2)) = v;
      }
      __syncthreads();
    }
    // syrk
    for (int i = p + 1; i < 8; ++i) {
      for (int j = p + 1; j <= i; ++j) {
        {
          const float* a = Mk + (size_t)((i << 6) + sr)*DIM + p0 + sq;
          const float* b = Mk + (size_t)((j << 6) + sr)*DIM + p0 + sq;
          #pragma unroll
          for (int t4 = 0; t4 < 4; ++t4) {
            float4 va = *(const float4*)(a + 4*t4);
            TA[(sq+4*t4+0)*68+sr]=va.x; TA[(sq+4*t4+1)*68+sr]=va.y;
            TA[(sq+4*t4+2)*68+sr]=va.z; TA[(sq+4*t4+3)*68+sr]=va.w;
            float4 vb = *(const float4*)(b + 4*t4);
            TB[(sq+4*t4+0)*68+sr]=vb.x; TB[(sq+4*t4+1)*68+sr]=vb.y;
            TB[(sq+4*t4+2)*68+sr]=vb.z; TB[(sq+4*t4+3)*68+sr]=vb.w;
          }
        }
        __syncthreads();
        float acc[4][4];
        #pragma unroll
        for (int a2 = 0; a2 < 4; ++a2)
          #pragma unroll
          for (int b2 = 0; b2 < 4; ++b2) acc[a2][b2] = 0.f;
        #pragma unroll 16
        for (int m = 0; m < 64; ++m) {
          float4 av = *(const float4*)(TA + m*68 + (ty << 2));
          float4 bv = *(const float4*)(TB + m*68 + (tx << 2));
          float a4[4] = {av.x, av.y, av.z, av.w};
          float b4[4] = {bv.x, bv.y, bv.z, bv.w};
          #pragma unroll
          for (int ir = 0; ir < 4; ++ir)
            #pragma unroll
            for (int ic = 0; ic < 4; ++ic) acc[ir][ic] += a4[ir] * b4[ic];
        }
        #pragma unroll
        for (int q = 0; q < 4; ++q) {
          float* dst = Mk + (size_t)((i << 6) + (ty << 2) + q)*DIM + (j << 6) + (tx << 2);
          float4 v = *(const float4*)dst;
          v.x -= acc[q][0]; v.y -= acc[q][1]; v.z -= acc[q][2]; v.w -= acc[q][3];
          *(float4*)dst = v;
        }
        __syncthreads();
      }
    }
  }
}

// Sweep iteration i: W_ij = -W_ii * (sum_{k=j}^{i-1} L_ik * W_kj) for all j < i.
// W f32 blocks live in M's upper triangle (block (j,k) holds W_kj); diag holds
// W_ii = inv(L_ii). One WG per (class, j). Emits bf16 W block (i,j).
__global__ __launch_bounds__(256) void sweep_kernel(float* __restrict__ M,
                                                    short* __restrict__ Wb, int i) {
  __shared__ float TL[64 * 68];
  __shared__ float TW[64 * 68];
  int cls = blockIdx.x / i;
  int j = blockIdx.x % i;
  float* Mk = M + (size_t)cls * DD;
  short* Wk = Wb + (size_t)cls * DD;
  int tid = threadIdx.x;
  int ty = tid >> 4, tx = tid & 15;
  int sr = tid >> 2, sq = (tid & 3) << 4;
  float acc[4][4];
  #pragma unroll
  for (int a = 0; a < 4; ++a)
    #pragma unroll
    for (int b = 0; b < 4; ++b) acc[a][b] = 0.f;
  for (int k = j; k < i; ++k) {
    __syncthreads();
    {
      const float* a = Mk + (size_t)((i << 6) + sr)*DIM + (k << 6) + sq;
      const float* b = Mk + (size_t)((j << 6) + sr)*DIM + (k << 6) + sq;
      #pragma unroll
      for (int t4 = 0; t4 < 4; ++t4) {
        float4 va = *(const float4*)(a + 4*t4);
        TL[(sq+4*t4+0)*68+sr]=va.x; TL[(sq+4*t4+1)*68+sr]=va.y;
        TL[(sq+4*t4+2)*68+sr]=va.z; TL[(sq+4*t4+3)*68+sr]=va.w;
        *(float4*)(TW + sr*68 + sq + 4*t4) = *(const float4*)(b + 4*t4);
      }
    }
    __syncthreads();
    #pragma unroll 16
    for (int m = 0; m < 64; ++m) {
      float4 av = *(const float4*)(TL + m*68 + (ty << 2));
      float4 bv = *(const float4*)(TW + m*68 + (tx << 2));
      float a4[4] = {av.x, av.y, av.z, av.w};
      float b4[4] = {bv.x, bv.y, bv.z, bv.w};
      #pragma unroll
      for (int ir = 0; ir < 4; ++ir)
        #pragma unroll
        for (int ic = 0; ic < 4; ++ic) acc[ir][ic] += a4[ir] * b4[ic];
    }
  }
  __syncthreads();
  #pragma unroll
  for (int q = 0; q < 4; ++q) {
    float4 v; v.x = acc[q][0]; v.y = acc[q][1]; v.z = acc[q][2]; v.w = acc[q][3];
    *(float4*)(TW + ((ty << 2) + q)*68 + (tx << 2)) = v;
  }
  {
    const float* a = Mk + (size_t)((i << 6) + sr)*DIM + (i << 6) + sq;
    #pragma unroll
    for (int t4 = 0; t4 < 4; ++t4) {
      float4 va = *(const float4*)(a + 4*t4);
      TL[(sq+4*t4+0)*68+sr]=va.x; TL[(sq+4*t4+1)*68+sr]=va.y;
      TL[(sq+4*t4+2)*68+sr]=va.z; TL[(sq+4*t4+3)*68+sr]=va.w;
    }
  }
  __syncthreads();
  float r2[4][4];
  #pragma unroll
  for (int a = 0; a < 4; ++a)
    #pragma unroll
    for (int b = 0; b < 4; ++b) r2[a][b] = 0.f;
  #pragma unroll 16
  for (int m = 0; m < 64; ++m) {
    float4 av = *(const float4*)(TL + m*68 + (ty << 2));
    float4 bv = *(const float4*)(TW + m*68 + (tx << 2));
    float a4[4] = {av.x, av.y, av.z, av.w};
    float b4[4] = {bv.x, bv.y, bv.z, bv.w};
    #pragma unroll
    for (int ir = 0; ir < 4; ++ir)
      #pragma unroll
      for (int ic = 0; ic < 4; ++ic) r2[ir][ic] += a4[ir] * b4[ic];
  }
  #pragma unroll
  for (int q = 0; q < 4; ++q) {
    int a = (ty << 2) + q;
    float4 v; v.x = -r2[q][0]; v.y = -r2[q][1]; v.z = -r2[q][2]; v.w = -r2[q][3];
    *(float4*)(Mk + (size_t)((j << 6) + a)*DIM + (i << 6) + (tx << 2)) = v;
    s16x4 h;
    h[0] = f2bf(v.x); h[1] = f2bf(v.y); h[2] = f2bf(v.z); h[3] = f2bf(v.w);
    *(s16x4*)(Wk + (size_t)((i << 6) + a)*DIM + (j << 6) + (tx << 2)) = h;
  }
}

// scores via bf16 MFMA. A-fragments in registers (loaded once from global),
// jt-outer loop (single 16-reg accumulator), double-buffered W staging with
// issue-early/write-late pipeline, 1 barrier per stage.
__global__ __launch_bounds__(256, 3) void score_kernel(const float* __restrict__ X,
                                                       const float* __restrict__ muK,
                                                       const float* __restrict__ cK,
                                                       const short* __restrict__ W,
                                                       const float* __restrict__ aux,
                                                       float* __restrict__ out) {
  __shared__ __align__(16) short WBs[2][4096];
  __shared__ float sred[4];
  int bid = blockIdx.x;
  int kc = bid >> 5;
  int n0 = (bid & 31) << 6;
  int tid = threadIdx.x;
  int lane = tid & 63, wv = tid >> 6;
  int srow = tid >> 2;
  int sc4 = (tid & 3) << 4;
  const short* Wk = W + (size_t)kc * DD;
  const float* mu = muK + (size_t)kc * DIM;
  int r16 = lane & 15;
  int k8 = (lane >> 4) << 3;
  int arow = (wv << 4) + r16;

  // A fragments (diff in bf16), loaded once: af[dc][ks]
  bf16x8 af[8][2];
  #pragma unroll
  for (int dc = 0; dc < 8; ++dc) {
    #pragma unroll
    for (int ks = 0; ks < 2; ++ks) {
      int col = (dc << 6) + (ks << 5) + k8;
      const float* xp = X + (size_t)(n0 + arow)*DIM + col;
      float4 x0 = *(const float4*)xp;
      float4 x1 = *(const float4*)(xp + 4);
      float4 m0 = *(const float4*)(mu + col);
      float4 m1 = *(const float4*)(mu + col + 4);
      bf16x8 h;
      h[0]=f2bf(x0.x-m0.x); h[1]=f2bf(x0.y-m0.y); h[2]=f2bf(x0.z-m0.z); h[3]=f2bf(x0.w-m0.w);
      h[4]=f2bf(x1.x-m1.x); h[5]=f2bf(x1.y-m1.y); h[6]=f2bf(x1.z-m1.z); h[7]=f2bf(x1.w-m1.w);
      af[dc][ks] = h;
    }
  }
  // sum(cK) partial (per-wave)
  {
    float v = (tid < NCLS) ? cK[tid] : 0.f;
    #pragma unroll
    for (int o = 32; o > 0; o >>= 1) v += __shfl_xor(v, o);
    if (lane == 0) sred[wv] = v;
  }
  int sb0 = ((srow << 7) + (sc4 << 1)) ^ ((srow & 7) << 4);
  int sb1 = ((srow << 7) + (sc4 << 1) + 16) ^ ((srow & 7) << 4);

  // staging pipeline prologue: rg[s&1] holds data(s)
  uint4 rg[2][2];
  {
    const uint4* p0 = (const uint4*)(Wk + (size_t)srow*DIM + sc4);               // (0,0)
    rg[0][0] = p0[0]; rg[0][1] = p0[1];
  }
  *(uint4*)((char*)WBs[0] + sb0) = rg[0][0];
  *(uint4*)((char*)WBs[0] + sb1) = rg[0][1];
  {
    const uint4* p1 = (const uint4*)(Wk + (size_t)(64 + srow)*DIM + sc4);        // (1,0)
    rg[1][0] = p1[0]; rg[1][1] = p1[1];
  }
  __syncthreads();
  float sumck = sred[0] + sred[1] + sred[2] + sred[3];

  float qp[4] = {0.f, 0.f, 0.f, 0.f};
  #pragma unroll
  for (int jt = 0; jt < 8; ++jt) {
    f32x4 acc[4];
    #pragma unroll
    for (int jj = 0; jj < 4; ++jj) { acc[jj][0]=0.f; acc[jj][1]=0.f; acc[jj][2]=0.f; acc[jj][3]=0.f; }
    #pragma unroll
    for (int dc = 0; dc <= jt; ++dc) {
      const int s = (jt * (jt + 1)) / 2 + dc;
      const int ns = s + 1;
      if (ns < 36) {   // stage data(s+1) into the other buffer
        *(uint4*)((char*)WBs[ns & 1] + sb0) = rg[ns & 1][0];
        *(uint4*)((char*)WBs[ns & 1] + sb1) = rg[ns & 1][1];
      }
      if (s + 2 < 36) {   // issue loads for data(s+2)
        int njt = (dc < jt) ? jt : jt + 1;
        int ndc = (dc < jt) ? dc + 1 : 0;
        int jt2 = njt, dc2 = ndc + 1;
        if (dc2 > jt2) { jt2 += 1; dc2 = 0; }
        const uint4* pp = (const uint4*)(Wk + (size_t)((jt2 << 6) + srow)*DIM + (dc2 << 6) + sc4);
        rg[s & 1][0] = pp[0]; rg[s & 1][1] = pp[1];
      }
      __builtin_amdgcn_s_setprio(1);
      #pragma unroll
      for (int ks = 0; ks < 2; ++ks) {
        #pragma unroll
        for (int jj = 0; jj < 4; ++jj) {
          int brow = (jj << 4) + r16;
          bf16x8 bfr = *(const bf16x8*)((const char*)WBs[s & 1] +
                       (((brow << 7) + (((ks << 5) + k8) << 1)) ^ ((brow & 7) << 4)));
          acc[jj] = __builtin_amdgcn_mfma_f32_16x16x32_bf16(af[dc][ks], bfr, acc[jj], 0, 0, 0);
        }
      }
      __builtin_amdgcn_s_setprio(0);
      __syncthreads();
    }
    #pragma unroll
    for (int jj = 0; jj < 4; ++jj)
      #pragma unroll
      for (int r = 0; r < 4; ++r) { float y = acc[jj][r]; qp[r] += y * y; }
  }
  #pragma unroll
  for (int r = 0; r < 4; ++r) {
    qp[r] += __shfl_xor(qp[r], 1);
    qp[r] += __shfl_xor(qp[r], 2);
    qp[r] += __shfl_xor(qp[r], 4);
    qp[r] += __shfl_xor(qp[r], 8);
  }
  float ck = cK[kc];
  float base;
  if (ck == 0.f) base = -INFINITY;
  else base = logf(ck) - logf(sumck) - 0.25f * logf(aux[1 + kc]);
  if ((lane & 15) == 0) {
    int nbase = n0 + (wv << 4) + ((lane >> 4) << 2);
    #pragma unroll
    for (int r = 0; r < 4; ++r)
      out[(size_t)(nbase + r)*NCLS + kc] = base - 0.5f * qp[r];
  }
}

extern "C" void kernel_launch(void* const* d_in, const int* in_sizes, int n_in,
                              void* d_out, int out_size, void* d_ws, size_t ws_size,
                              hipStream_t stream) {
  (void)in_sizes; (void)n_in; (void)out_size; (void)ws_size;
  const float* X      = (const float*)d_in[0];
  const float* muK    = (const float*)d_in[1];
  const float* SigmaK = (const float*)d_in[2];
  const float* Sigma  = (const float*)d_in[3];
  const float* cK     = (const float*)d_in[4];
  float* out = (float*)d_out;
  char* ws = (char*)d_ws;
  float* M   = (float*)ws;                                   // 104857600 B
  short* W   = (short*)(ws + (size_t)NCLS * DD * 4);         //  52428800 B
  float* aux = (float*)(ws + (size_t)NCLS * DD * 6);         //       404 B

  hipMemsetAsync(aux, 0, (1 + NCLS) * sizeof(float), stream);
  prep_kernel<<<400, 256, 0, stream>>>(SigmaK, Sigma, M, aux);
  for (int p = 0; p < 4; ++p) {
    fdt_kernel<<<NCLS, 256, 0, stream>>>(M, W, p);
    int n = 7 - p;
    syrk_kernel<<<NCLS * (n * (n + 1) / 2), 256, 0, stream>>>(M, p);
  }
  tail_kernel<<<NCLS, 256, 0, stream>>>(M, W);
  for (int i = 1; i < 8; ++i)
    sweep_kernel<<<NCLS * i, 256, 0, stream>>>(M, W, i);
  score_kernel<<<NCLS * 32, 256, 0, stream>>>(X, muK, cK, W, aux, out);
}